// Round 12
// baseline (423.113 us; speedup 1.0000x reference)
//
#include <hip/hip_runtime.h>
#include <cstdint>
#include <cstddef>

// Problem constants
constexpr int T_N = 8192;   // rows of x / out
constexpr int MM  = 4096;   // K (cols of x, cols of W)
constexpr int NN  = 4096;   // rows of W / cols of out
constexpr int S_L = 2048;
constexpr int S_R = 2048;
constexpr float EPS_ = 1e-6f;

typedef float  f32x4   __attribute__((ext_vector_type(4)));
typedef __bf16 bf16x8  __attribute__((ext_vector_type(8)));
typedef unsigned short ushort8 __attribute__((ext_vector_type(8)));

__device__ __forceinline__ unsigned short f2bf(float f) {
  unsigned int u = __float_as_uint(f);
  u += 0x7FFFu + ((u >> 16) & 1u);   // round-to-nearest-even
  return (unsigned short)(u >> 16);
}

// ---------------------------------------------------------------------------
// Kernel 1: identity column maps
// ---------------------------------------------------------------------------
__global__ void init_cols(float* colC, float* colS, int* colP) {
  int i = blockIdx.x * blockDim.x + threadIdx.x;
  if (i < MM) { colC[i] = 1.f; colS[i] = 0.f; colP[i] = i; }
}

// ---------------------------------------------------------------------------
// Kernel 2: column rotation maps from (pairs_R, theta_R).
// ---------------------------------------------------------------------------
__global__ void build_cols(const float* __restrict__ thR, const int* __restrict__ prR,
                           float* colC, float* colS, int* colP) {
  int s = blockIdx.x * blockDim.x + threadIdx.x;
  if (s < S_R) {
    int i = prR[2*s], j = prR[2*s+1];
    float c = cosf(thR[s]), sn = sinf(thR[s]);
    colC[i] = c; colS[i] = -sn; colP[i] = j;
    colC[j] = c; colS[j] =  sn; colP[j] = i;
  }
}

// ---------------------------------------------------------------------------
// Kernel 3 (fused): bid < S_L  -> W_eff pair build;  bid >= S_L -> x -> bf16
// ---------------------------------------------------------------------------
__global__ __launch_bounds__(256) void weff_conv(
    const float* __restrict__ W, const float* __restrict__ brn, const float* __restrict__ elm,
    const float* __restrict__ thL, const int* __restrict__ prL,
    const float* __restrict__ colC, const float* __restrict__ colS, const int* __restrict__ colP,
    unsigned short* __restrict__ Wb,
    const float* __restrict__ x, unsigned short* __restrict__ xb)
{
  __shared__ __align__(16) float rI[MM];
  __shared__ __align__(16) float rJ[MM];
  __shared__ float red[8];

  int bid = blockIdx.x;
  int tid = threadIdx.x;

  if (bid >= S_L) {
    const size_t total = (size_t)T_N * MM / 8;
    for (size_t i = (size_t)(bid - S_L) * 256 + tid; i < total; i += 2048ull * 256ull) {
      const float* s = x + i * 8;
      f32x4 v0 = *(const f32x4*)s;
      f32x4 v1 = *(const f32x4*)(s + 4);
      ushort8 p;
      p[0] = f2bf(v0.x); p[1] = f2bf(v0.y); p[2] = f2bf(v0.z); p[3] = f2bf(v0.w);
      p[4] = f2bf(v1.x); p[5] = f2bf(v1.y); p[6] = f2bf(v1.z); p[7] = f2bf(v1.w);
      *(ushort8*)(xb + i * 8) = p;
    }
    return;
  }

  int s = bid;
  int i = prL[2*s], j = prL[2*s+1];
  float cl = cosf(thL[s]), sl = sinf(thL[s]);
  const float* Wi = W + (size_t)i * MM;
  const float* Wj = W + (size_t)j * MM;

  for (int m = tid * 4; m < MM; m += 1024) {
    *(f32x4*)&rI[m] = *(const f32x4*)&Wi[m];
    *(f32x4*)&rJ[m] = *(const f32x4*)&Wj[m];
  }
  __syncthreads();

  float ssi = 0.f, ssj = 0.f;
  for (int m = tid; m < MM; m += 256) {
    int p = colP[m];
    float c = colC[m], sn = colS[m];
    float vi = c * rI[m] + sn * rI[p];
    float vj = c * rJ[m] + sn * rJ[p];
    float ei = cl * vi - sl * vj;
    float ej = sl * vi + cl * vj;
    ssi += ei * ei;
    ssj += ej * ej;
  }
  #pragma unroll
  for (int o = 32; o; o >>= 1) { ssi += __shfl_xor(ssi, o); ssj += __shfl_xor(ssj, o); }
  int lane = tid & 63, wid = tid >> 6;
  if (lane == 0) { red[wid] = ssi; red[4 + wid] = ssj; }
  __syncthreads();
  float ti = red[0] + red[1] + red[2] + red[3];
  float tj = red[4] + red[5] + red[6] + red[7];
  float sci = brn[i] * expf(elm[i]) / sqrtf(ti + EPS_);
  float scj = brn[j] * expf(elm[j]) / sqrtf(tj + EPS_);

  for (int m0 = tid * 8; m0 < MM; m0 += 2048) {
    ushort8 pi, pj;
    #pragma unroll
    for (int q = 0; q < 8; q++) {
      int m = m0 + q;
      int p = colP[m];
      float c = colC[m], sn = colS[m];
      float vi = c * rI[m] + sn * rI[p];
      float vj = c * rJ[m] + sn * rJ[p];
      pi[q] = f2bf((cl * vi - sl * vj) * sci);
      pj[q] = f2bf((sl * vi + cl * vj) * scj);
    }
    *(ushort8*)&Wb[(size_t)i * MM + m0] = pi;
    *(ushort8*)&Wb[(size_t)j * MM + m0] = pj;
  }
}

// ---------------------------------------------------------------------------
// global->LDS async staging helper (16B, linear LDS dest)
// ---------------------------------------------------------------------------
typedef const __attribute__((address_space(1))) unsigned int* as1_u32p;
typedef __attribute__((address_space(3))) unsigned int* as3_u32p;

__device__ __forceinline__ void gl_lds16(const void* g, void* l) {
  __builtin_amdgcn_global_load_lds((as1_u32p)g, (as3_u32p)l, 16, 0, 0);
}

// ---------------------------------------------------------------------------
// Kernel 5a: 256x256 GEMM — 4-wave (1/SIMD) fat-wave schedule.
//   Per wave: output 128x128, acc[8][8] f32x4 (256 AGPR).  16x16x32 bf16.
//   LDS reads/tile/CU: 4 waves x 32 b128 = 128 (vs 192 with 8 waves, -33%)
//   -> LDS pipe drops below the MFMA floor; MFMA becomes the binding pipe.
//   In-wave pipeline (no co-wave): pinned read order (SB0 per group) +
//   counted-lgkm ladder (gfx950 lgkmcnt max = 15: first rung 15 retires
//   b0+a0); per-ni kk0-pass then kk1-pass (dependent same-acc MFMAs 8
//   apart); b[s+2] trickled at ni-step ends; stage chunks at ni=0..2 ends;
//   ONE barrier + vmcnt(0)-with-~1500-cyc-cover per tile.
//   Ladder ledger (20 ds_reads outstanding at start: b0=2,a0..a7=16,b1=2):
//   rung for MFK(m,0,0) needs outstanding <= 16-2m -> 15,14,12,10,8,6,4,2;
//   kk1 pass behind lgkm(2) (only b1 left); b[s] for NISTEP(s) retired by
//   the lgkm(2) at its head (b[s+1..] outstanding).
//   Swizzle (r2/r9-verified, 0 conflicts): stage src col-group ^= (row&7);
//   read byte addr: row*128 + ((kk*64+lg*16) ^ ((lr&7)<<4)).
// ---------------------------------------------------------------------------
constexpr int GBM = 256, GBN = 256, GBK = 64;
constexpr int NTK = MM / GBK;              // 64 K-tiles
constexpr int BUFB = GBM * GBK * 2;        // 32 KiB per operand per buffer

#define SB0() __builtin_amdgcn_sched_barrier(0)
#define BAR() __builtin_amdgcn_s_barrier()
#define LGKMN(N) do { asm volatile("s_waitcnt lgkmcnt(" #N ")" ::: "memory"); \
                      SB0(); } while (0)
#define VMC0() asm volatile("s_waitcnt vmcnt(0)" ::: "memory")

// one MFMA: acc[M][N] += a[M][K] * b[N][K]
#define MFK(M, N, K)                                                          \
  acc[M][N] = __builtin_amdgcn_mfma_f32_16x16x32_bf16(a[M][K], b[N][K],       \
                                                      acc[M][N], 0, 0, 0);

// full ni-step for n>=1 (reads done): kk0 pass then kk1 pass
#define NISTEP(N)                                                             \
  MFK(0, N, 0) MFK(1, N, 0) MFK(2, N, 0) MFK(3, N, 0)                         \
  MFK(4, N, 0) MFK(5, N, 0) MFK(6, N, 0) MFK(7, N, 0)                         \
  MFK(0, N, 1) MFK(1, N, 1) MFK(2, N, 1) MFK(3, N, 1)                         \
  MFK(4, N, 1) MFK(5, N, 1) MFK(6, N, 1) MFK(7, N, 1)

// read B frag pair for ni=N (kk0, kk1), pinned
#define RDB(N)                                                                \
  b[N][0] = *(const bf16x8*)(bK0 + (N) * 2048);                               \
  b[N][1] = *(const bf16x8*)(bK1 + (N) * 2048);                               \
  SB0();

// stage chunk CC (4 gl_lds: A granules 2CC,2CC+1; B same) for next tile
#define STGC(KOF, AN, BN, CC)                                                 \
  gl_lds16(sA + (size_t)(2*(CC))   * (32 * MM) + (KOF), (AN) + dstb + (2*(CC))   * 4096); \
  gl_lds16(sA + (size_t)(2*(CC)+1) * (32 * MM) + (KOF), (AN) + dstb + (2*(CC)+1) * 4096); \
  gl_lds16(sB + (size_t)(2*(CC))   * (32 * MM) + (KOF), (BN) + dstb + (2*(CC))   * 4096); \
  gl_lds16(sB + (size_t)(2*(CC)+1) * (32 * MM) + (KOF), (BN) + dstb + (2*(CC)+1) * 4096);

__global__ __launch_bounds__(256, 1) void gemm4(
    const unsigned short* __restrict__ xb,
    const unsigned short* __restrict__ wb,
    const float* __restrict__ bias,
    float* __restrict__ C)
{
  __shared__ __align__(16) unsigned short As[2 * GBM * GBK];  // 64 KiB
  __shared__ __align__(16) unsigned short Bs[2 * GBN * GBK];  // 64 KiB
  char* ldsA = (char*)As;
  char* ldsB = (char*)Bs;

  // grid = 512 = 32 (tm) x 16 (tn); XCD swizzle, tn-fast within an XCD.
  int bid = blockIdx.x;
  int swz = (bid & 7) * 64 + (bid >> 3);
  int tn = swz & 15, tm = swz >> 4;
  const int trow0 = tm * GBM;
  const int tcol0 = tn * GBN;

  int tid  = threadIdx.x;
  int lane = tid & 63;
  int wv   = tid >> 6;               // 4 waves
  int wr = wv >> 1, wc = wv & 1;     // wave grid 2x2, wave tile 128x128
  int lr = lane & 15;                // fragment row/col
  int lg = lane >> 4;                // k-group (8 bf16 = 16B)
  const int sw = (lr & 7) << 4;      // swizzle byte term
  const int koff0 = (lg * 16) ^ sw;
  const int koff1 = (64 + lg * 16) ^ sw;
  const int arow0 = (wr * 128 + lr) * 128;  // A row base bytes (+ mi*2048)
  const int brow0 = (wc * 128 + lr) * 128;  // B row base bytes (+ ni*2048)

  // staging geometry: granule l covers rows r0 + 32*l; const col group
  const int r0   = tid >> 3;                          // 0..31
  const int colg = (tid & 7) ^ (r0 & 7);
  const unsigned short* sA = xb + (size_t)(trow0 + r0) * MM + colg * 8;
  const unsigned short* sB = wb + (size_t)(tcol0 + r0) * MM + colg * 8;
  const int dstb = tid * 16;

  f32x4 acc[8][8];
  #pragma unroll
  for (int i = 0; i < 8; i++)
    #pragma unroll
    for (int j = 0; j < 8; j++) {
      f32x4 z = {0.f, 0.f, 0.f, 0.f};
      acc[i][j] = z;
    }

  // ---- prologue: stage tile 0 fully into buf0 (16 gl/thread), drain ----
  {
    char* A0 = ldsA; char* B0 = ldsB;
    STGC(0, A0, B0, 0) STGC(0, A0, B0, 1) STGC(0, A0, B0, 2) STGC(0, A0, B0, 3)
  }
  VMC0();
  BAR();

  // ---- main loop: one barrier + one (covered) vmcnt(0) per tile ----
  #pragma unroll 1
  for (int t = 0; t < NTK; ++t) {
    const int cur = t & 1;
    char* Anxt = ldsA + (cur ^ 1) * BUFB;
    char* Bnxt = ldsB + (cur ^ 1) * BUFB;
    const char* aK0 = ldsA + cur * BUFB + arow0 + koff0;
    const char* aK1 = ldsA + cur * BUFB + arow0 + koff1;
    const char* bK0 = ldsB + cur * BUFB + brow0 + koff0;
    const char* bK1 = ldsB + cur * BUFB + brow0 + koff1;
    const int kof1 = (t + 1) * GBK;
    const bool st = (t + 1 < NTK);

    bf16x8 a[8][2], b[8][2];

    // ---- pinned issue: b0 | a0..a7 | b1 | stage chunk 0 ----
    RDB(0)
    #pragma unroll
    for (int m = 0; m < 8; ++m) {
      a[m][0] = *(const bf16x8*)(aK0 + m * 2048);
      a[m][1] = *(const bf16x8*)(aK1 + m * 2048);
      SB0();
    }
    RDB(1)
    if (st) { STGC(kof1, Anxt, Bnxt, 0) }
    SB0();

    // ---- ni = 0: counted-lgkm ladder through kk0 pass ----
    LGKMN(15); MFK(0, 0, 0)
    LGKMN(14); MFK(1, 0, 0)
    LGKMN(12); MFK(2, 0, 0)
    LGKMN(10); MFK(3, 0, 0)
    LGKMN(8);  MFK(4, 0, 0)
    LGKMN(6);  MFK(5, 0, 0)
    LGKMN(4);  MFK(6, 0, 0)
    LGKMN(2);  MFK(7, 0, 0)
    MFK(0, 0, 1) MFK(1, 0, 1) MFK(2, 0, 1) MFK(3, 0, 1)
    MFK(4, 0, 1) MFK(5, 0, 1) MFK(6, 0, 1) MFK(7, 0, 1)
    RDB(2)
    if (st) { STGC(kof1, Anxt, Bnxt, 1) }
    SB0();

    LGKMN(2);  NISTEP(1)
    RDB(3)
    if (st) { STGC(kof1, Anxt, Bnxt, 2) }
    SB0();

    LGKMN(2);  NISTEP(2)
    RDB(4)
    if (st) { STGC(kof1, Anxt, Bnxt, 3) }
    SB0();

    LGKMN(2);  NISTEP(3)
    RDB(5)

    LGKMN(2);  NISTEP(4)
    RDB(6)

    LGKMN(2);  NISTEP(5)
    RDB(7)

    LGKMN(2);  NISTEP(6)

    LGKMN(0);  NISTEP(7)

    if (st) { VMC0(); }   // last stage issued ~5 ni-steps (~1500 cyc) ago
    BAR();
  }

  // ---- epilogue: C/D layout col = lane&15, row = (lane>>4)*4 + reg ----
  #pragma unroll
  for (int ni = 0; ni < 8; ++ni) {
    int col = tcol0 + wc * 128 + ni * 16 + lr;
    float bi = bias[col];
    #pragma unroll
    for (int mi = 0; mi < 8; ++mi) {
      int rr0 = trow0 + wr * 128 + mi * 16 + lg * 4;
      #pragma unroll
      for (int qq = 0; qq < 4; ++qq)
        C[(size_t)(rr0 + qq) * NN + col] = acc[mi][ni][qq] + bi;
    }
  }
}

// ---------------------------------------------------------------------------
// Kernel 5b (fallback, ws too small for xb): m97-style 128x128 GEMM with
// inline f32->bf16 A-staging.
// ---------------------------------------------------------------------------
constexpr int BM = 128, BN = 128, BK = 64;

__global__ __launch_bounds__(256) void gemm_fb(
    const float* __restrict__ xf,
    const unsigned short* __restrict__ wb, const float* __restrict__ bias,
    float* __restrict__ C)
{
  __shared__ __align__(16) unsigned short As2[BM * BK];
  __shared__ __align__(16) unsigned short Bs2[BN * BK];

  int bid = blockIdx.x;
  int swz = (bid & 7) * 256 + (bid >> 3);
  int tn = swz & 31;
  int tm = swz >> 5;

  int tid  = threadIdx.x;
  int lane = tid & 63;
  int wid  = tid >> 6;
  int wr = wid >> 1, wc = wid & 1;
  int lr = lane & 15;
  int lg = lane >> 4;

  f32x4 acc[4][4];
  #pragma unroll
  for (int i = 0; i < 4; i++)
    #pragma unroll
    for (int j = 0; j < 4; j++) {
      f32x4 z = {0.f, 0.f, 0.f, 0.f};
      acc[i][j] = z;
    }

  int srow = tid >> 3;
  int scol = (tid & 7) * 8;
  const size_t a_base = (size_t)(tm * BM) * MM;
  const size_t b_base = (size_t)(tn * BN) * MM;

  for (int k0 = 0; k0 < MM; k0 += BK) {
    #pragma unroll
    for (int c = 0; c < 4; c++) {
      int row = c * 32 + srow;
      gl_lds16(wb + b_base + (size_t)row * MM + k0 + scol,
               (char*)Bs2 + (c * 256 + wid * 64) * 16);
    }
    #pragma unroll
    for (int c = 0; c < 4; c++) {
      int row = c * 32 + srow;
      const float* s = xf + a_base + (size_t)row * MM + k0 + scol;
      f32x4 v0 = *(const f32x4*)s;
      f32x4 v1 = *(const f32x4*)(s + 4);
      ushort8 p;
      p[0] = f2bf(v0.x); p[1] = f2bf(v0.y); p[2] = f2bf(v0.z); p[3] = f2bf(v0.w);
      p[4] = f2bf(v1.x); p[5] = f2bf(v1.y); p[6] = f2bf(v1.z); p[7] = f2bf(v1.w);
      *(ushort8*)&As2[(c * 256 + tid) * 8] = p;
    }
    __syncthreads();

    #pragma unroll
    for (int kk = 0; kk < 2; kk++) {
      bf16x8 a[4], b[4];
      #pragma unroll
      for (int i = 0; i < 4; i++) {
        a[i] = *(const bf16x8*)&As2[(wr * 64 + i * 16 + lr) * BK + kk * 32 + lg * 8];
        b[i] = *(const bf16x8*)&Bs2[(wc * 64 + i * 16 + lr) * BK + kk * 32 + lg * 8];
      }
      #pragma unroll
      for (int i = 0; i < 4; i++)
        #pragma unroll
        for (int j = 0; j < 4; j++)
          acc[i][j] = __builtin_amdgcn_mfma_f32_16x16x32_bf16(a[i], b[j], acc[i][j], 0, 0, 0);
    }
    __syncthreads();
  }

  int gn0 = tn * BN + wc * 64;
  int gt0 = tm * BM + wr * 64;
  #pragma unroll
  for (int j = 0; j < 4; j++) {
    int gn = gn0 + j * 16 + lr;
    float bi = bias[gn];
    #pragma unroll
    for (int i = 0; i < 4; i++) {
      int t0 = gt0 + i * 16 + lg * 4;
      #pragma unroll
      for (int q = 0; q < 4; q++)
        C[(size_t)(t0 + q) * NN + gn] = acc[i][j][q] + bi;
    }
  }
}

// ---------------------------------------------------------------------------
extern "C" void kernel_launch(void* const* d_in, const int* in_sizes, int n_in,
                              void* d_out, int out_size, void* d_ws, size_t ws_size,
                              hipStream_t stream)
{
  const float* x    = (const float*)d_in[0];
  const float* W    = (const float*)d_in[1];
  const float* bias = (const float*)d_in[2];
  const float* thL  = (const float*)d_in[3];
  const float* thR  = (const float*)d_in[4];
  const float* elm  = (const float*)d_in[5];
  const float* brn  = (const float*)d_in[6];
  const int*   prL  = (const int*)d_in[7];
  const int*   prR  = (const int*)d_in[8];
  float* out = (float*)d_out;

  char* ws = (char*)d_ws;
  unsigned short* Wb = (unsigned short*)ws;          // N*M bf16 = 33.5 MB
  size_t off = (size_t)NN * MM * 2;
  float* colC = (float*)(ws + off); off += MM * 4;
  float* colS = (float*)(ws + off); off += MM * 4;
  int*   colP = (int*)  (ws + off); off += MM * 4;
  unsigned short* xb = (unsigned short*)(ws + off);  // T*M bf16 = 67 MB
  bool use_xb = ws_size >= off + (size_t)T_N * MM * 2;

  init_cols <<<16, 256, 0, stream>>>(colC, colS, colP);
  build_cols<<< 8, 256, 0, stream>>>(thR, prR, colC, colS, colP);

  if (use_xb) {
    weff_conv<<<S_L + 2048, 256, 0, stream>>>(W, brn, elm, thL, prL,
                                              colC, colS, colP, Wb, x, xb);
    gemm4<<<512, 256, 0, stream>>>(xb, Wb, bias, out);
  } else {
    weff_conv<<<S_L, 256, 0, stream>>>(W, brn, elm, thL, prL,
                                       colC, colS, colP, Wb, x, xb);
    gemm_fb<<<2048, 256, 0, stream>>>(x, Wb, bias, out);
  }
}

// Round 13
// 302.323 us; speedup vs baseline: 1.3995x; 1.3995x over previous
//
#include <hip/hip_runtime.h>
#include <cstdint>
#include <cstddef>

// Problem constants
constexpr int T_N = 8192;   // rows of x / out
constexpr int MM  = 4096;   // K (cols of x, cols of W)
constexpr int NN  = 4096;   // rows of W / cols of out
constexpr int S_L = 2048;
constexpr int S_R = 2048;
constexpr float EPS_ = 1e-6f;

typedef float  f32x4   __attribute__((ext_vector_type(4)));
typedef __bf16 bf16x8  __attribute__((ext_vector_type(8)));
typedef unsigned short ushort8 __attribute__((ext_vector_type(8)));

__device__ __forceinline__ unsigned short f2bf(float f) {
  unsigned int u = __float_as_uint(f);
  u += 0x7FFFu + ((u >> 16) & 1u);   // round-to-nearest-even
  return (unsigned short)(u >> 16);
}

// ---------------------------------------------------------------------------
// Kernel 1: identity column maps
// ---------------------------------------------------------------------------
__global__ void init_cols(float* colC, float* colS, int* colP) {
  int i = blockIdx.x * blockDim.x + threadIdx.x;
  if (i < MM) { colC[i] = 1.f; colS[i] = 0.f; colP[i] = i; }
}

// ---------------------------------------------------------------------------
// Kernel 2: column rotation maps from (pairs_R, theta_R).
// ---------------------------------------------------------------------------
__global__ void build_cols(const float* __restrict__ thR, const int* __restrict__ prR,
                           float* colC, float* colS, int* colP) {
  int s = blockIdx.x * blockDim.x + threadIdx.x;
  if (s < S_R) {
    int i = prR[2*s], j = prR[2*s+1];
    float c = cosf(thR[s]), sn = sinf(thR[s]);
    colC[i] = c; colS[i] = -sn; colP[i] = j;
    colC[j] = c; colS[j] =  sn; colP[j] = i;
  }
}

// ---------------------------------------------------------------------------
// Kernel 3 (fused): bid < S_L  -> W_eff pair build;  bid >= S_L -> x -> bf16
// ---------------------------------------------------------------------------
__global__ __launch_bounds__(256) void weff_conv(
    const float* __restrict__ W, const float* __restrict__ brn, const float* __restrict__ elm,
    const float* __restrict__ thL, const int* __restrict__ prL,
    const float* __restrict__ colC, const float* __restrict__ colS, const int* __restrict__ colP,
    unsigned short* __restrict__ Wb,
    const float* __restrict__ x, unsigned short* __restrict__ xb)
{
  __shared__ __align__(16) float rI[MM];
  __shared__ __align__(16) float rJ[MM];
  __shared__ float red[8];

  int bid = blockIdx.x;
  int tid = threadIdx.x;

  if (bid >= S_L) {
    const size_t total = (size_t)T_N * MM / 8;
    for (size_t i = (size_t)(bid - S_L) * 256 + tid; i < total; i += 2048ull * 256ull) {
      const float* s = x + i * 8;
      f32x4 v0 = *(const f32x4*)s;
      f32x4 v1 = *(const f32x4*)(s + 4);
      ushort8 p;
      p[0] = f2bf(v0.x); p[1] = f2bf(v0.y); p[2] = f2bf(v0.z); p[3] = f2bf(v0.w);
      p[4] = f2bf(v1.x); p[5] = f2bf(v1.y); p[6] = f2bf(v1.z); p[7] = f2bf(v1.w);
      *(ushort8*)(xb + i * 8) = p;
    }
    return;
  }

  int s = bid;
  int i = prL[2*s], j = prL[2*s+1];
  float cl = cosf(thL[s]), sl = sinf(thL[s]);
  const float* Wi = W + (size_t)i * MM;
  const float* Wj = W + (size_t)j * MM;

  for (int m = tid * 4; m < MM; m += 1024) {
    *(f32x4*)&rI[m] = *(const f32x4*)&Wi[m];
    *(f32x4*)&rJ[m] = *(const f32x4*)&Wj[m];
  }
  __syncthreads();

  float ssi = 0.f, ssj = 0.f;
  for (int m = tid; m < MM; m += 256) {
    int p = colP[m];
    float c = colC[m], sn = colS[m];
    float vi = c * rI[m] + sn * rI[p];
    float vj = c * rJ[m] + sn * rJ[p];
    float ei = cl * vi - sl * vj;
    float ej = sl * vi + cl * vj;
    ssi += ei * ei;
    ssj += ej * ej;
  }
  #pragma unroll
  for (int o = 32; o; o >>= 1) { ssi += __shfl_xor(ssi, o); ssj += __shfl_xor(ssj, o); }
  int lane = tid & 63, wid = tid >> 6;
  if (lane == 0) { red[wid] = ssi; red[4 + wid] = ssj; }
  __syncthreads();
  float ti = red[0] + red[1] + red[2] + red[3];
  float tj = red[4] + red[5] + red[6] + red[7];
  float sci = brn[i] * expf(elm[i]) / sqrtf(ti + EPS_);
  float scj = brn[j] * expf(elm[j]) / sqrtf(tj + EPS_);

  for (int m0 = tid * 8; m0 < MM; m0 += 2048) {
    ushort8 pi, pj;
    #pragma unroll
    for (int q = 0; q < 8; q++) {
      int m = m0 + q;
      int p = colP[m];
      float c = colC[m], sn = colS[m];
      float vi = c * rI[m] + sn * rI[p];
      float vj = c * rJ[m] + sn * rJ[p];
      pi[q] = f2bf((cl * vi - sl * vj) * sci);
      pj[q] = f2bf((sl * vi + cl * vj) * scj);
    }
    *(ushort8*)&Wb[(size_t)i * MM + m0] = pi;
    *(ushort8*)&Wb[(size_t)j * MM + m0] = pj;
  }
}

// ---------------------------------------------------------------------------
// global->LDS async staging helper (16B, linear LDS dest)
// ---------------------------------------------------------------------------
typedef const __attribute__((address_space(1))) unsigned int* as1_u32p;
typedef __attribute__((address_space(3))) unsigned int* as3_u32p;

__device__ __forceinline__ void gl_lds16(const void* g, void* l) {
  __builtin_amdgcn_global_load_lds((as1_u32p)g, (as3_u32p)l, 16, 0, 0);
}

// ---------------------------------------------------------------------------
// Kernel 5a: 256x256 GEMM — exact m201 8-phase slot schedule (best measured:
//   242 us, MfmaUtil 50.3%, 0 bank conflicts — round 9).
//   BK=64, 8 waves (2Mx4N), per-wave 128x64, acc[8][4], 16x16x32 bf16 MFMA.
//   LDS 128 KiB dbuf.  8 phases per 2 K-tiles; each phase:
//     {ds_reads(12/8/4/0), stage ONE half-tile (2 gl_lds)} -> [lgkm(8) if 12]
//     -> bar -> lgkm(0) -> setprio(1) 16 MFMA setprio(0) -> bar
//   Stage slots (tile t even, buffers: t&1):
//     P1: B1(t+1)  P2: A0(t+2)  P3: A1(t+2)  P4: B0(t+2)  [vmcnt(6)]
//     P5: B1(t+2)  P6: A0(t+3)  P7: A1(t+3)  P8: B0(t+3)  [vmcnt(6)]
//   Ledger: each gate leaves exactly 3 half-tiles in flight; a tile is fully
//   retired at the gate before the phase that reads it (RAW).  Every stage
//   targets the region whose last ds_read completed one phase-barrier
//   earlier (WAR).  Quadrants: P1 Q1=A0xB0, P2 Q2=A1xB0, P3 Q3=A1xB1,
//   P4 Q4=A0xB1 (held regs, zero reads -> LDS catch-up window).
//   Swizzle (r2-verified, 0 conflicts): stage src col-group ^= (row&7);
//   read byte addr: row*128 + ((kk*64+lg*16) ^ ((lr&7)<<4)).
// ---------------------------------------------------------------------------
constexpr int GBM = 256, GBN = 256, GBK = 64;
constexpr int NTK = MM / GBK;              // 64 K-tiles
constexpr int BUFB = GBM * GBK * 2;        // 32 KiB per operand per buffer

#define SB0() __builtin_amdgcn_sched_barrier(0)
#define BAR() __builtin_amdgcn_s_barrier()
#define LGKM(N) do { asm volatile("s_waitcnt lgkmcnt(" #N ")" ::: "memory"); \
                     SB0(); } while (0)

#define RD_A8(DST, AB, MIH)                                                   \
  _Pragma("unroll") for (int i_ = 0; i_ < 4; ++i_)                            \
  _Pragma("unroll") for (int k_ = 0; k_ < 2; ++k_)                            \
    DST[i_][k_] = *(const bf16x8*)((AB) + arow0 + ((MIH) * 4 + i_) * 2048     \
                                    + ((k_ * 64 + lg * 16) ^ sw));

#define RD_B4(DST, BB, NIH)                                                   \
  _Pragma("unroll") for (int n_ = 0; n_ < 2; ++n_)                            \
  _Pragma("unroll") for (int k_ = 0; k_ < 2; ++k_)                            \
    DST[n_][k_] = *(const bf16x8*)((BB) + brow0 + ((NIH) * 2 + n_) * 2048     \
                                    + ((k_ * 64 + lg * 16) ^ sw));

#define QMF(AF, BF, MI0, NI0)                                                 \
  __builtin_amdgcn_s_setprio(1);                                              \
  _Pragma("unroll") for (int k_ = 0; k_ < 2; ++k_)                            \
  _Pragma("unroll") for (int i_ = 0; i_ < 4; ++i_)                            \
  _Pragma("unroll") for (int n_ = 0; n_ < 2; ++n_)                            \
    acc[(MI0) + i_][(NI0) + n_] = __builtin_amdgcn_mfma_f32_16x16x32_bf16(    \
        AF[i_][k_], BF[n_][k_], acc[(MI0) + i_][(NI0) + n_], 0, 0, 0);        \
  __builtin_amdgcn_s_setprio(0);

#define STG_A(KOF, BUF, H)                                                    \
  _Pragma("unroll") for (int l_ = 2 * (H); l_ < 2 * (H) + 2; ++l_)            \
    gl_lds16(sA + (size_t)l_ * (64 * MM) + (KOF),                             \
             ldsA + (BUF) * BUFB + dstb + l_ * 8192);
#define STG_B(KOF, BUF, H)                                                    \
  _Pragma("unroll") for (int l_ = 2 * (H); l_ < 2 * (H) + 2; ++l_)            \
    gl_lds16(sB + (size_t)l_ * (64 * MM) + (KOF),                             \
             ldsB + (BUF) * BUFB + dstb + l_ * 8192);

#define GATE6  asm volatile("s_waitcnt vmcnt(6)" ::: "memory")
#define GATE0v asm volatile("s_waitcnt vmcnt(0)" ::: "memory")
#define GNONE  do { } while (0)
#define NOST   do { } while (0)

// One K-tile = 4 phases.  ST1..ST4 are half-tile stage statements (or NOST);
// GATE fires in P4 before its barrier.
#define TILE4(T, BB, ST1, ST2, ST3, ST4, GATE)                                \
  {                                                                           \
    const char* Ab_ = ldsA + (BB) * BUFB;                                     \
    const char* Bb_ = ldsB + (BB) * BUFB;                                     \
    bf16x8 a0[4][2], a1[4][2], b0[2][2], b1[2][2];                            \
    /* P1: 12 reads; stage ST1; lgkm(8); Q1 = A0 x B0 */                      \
    RD_B4(b0, Bb_, 0);                                                        \
    RD_A8(a0, Ab_, 0);                                                        \
    SB0();                                                                    \
    ST1;                                                                      \
    LGKM(8);                                                                  \
    BAR();                                                                    \
    LGKM(0);                                                                  \
    QMF(a0, b0, 0, 0);                                                        \
    BAR();                                                                    \
    /* P2: 8 reads; stage ST2; Q2 = A1 x B0 */                                \
    RD_A8(a1, Ab_, 1);                                                        \
    SB0();                                                                    \
    ST2;                                                                      \
    BAR();                                                                    \
    LGKM(0);                                                                  \
    QMF(a1, b0, 4, 0);                                                        \
    BAR();                                                                    \
    /* P3: 4 reads; stage ST3; Q3 = A1 x B1 */                                \
    RD_B4(b1, Bb_, 1);                                                        \
    SB0();                                                                    \
    ST3;                                                                      \
    BAR();                                                                    \
    LGKM(0);                                                                  \
    QMF(a1, b1, 4, 2);                                                        \
    BAR();                                                                    \
    /* P4: 0 reads; stage ST4; gate; Q4 = A0 x B1 (held regs) */              \
    ST4;                                                                      \
    GATE;                                                                     \
    BAR();                                                                    \
    QMF(a0, b1, 0, 2);                                                        \
    BAR();                                                                    \
  }

__global__ __launch_bounds__(512, 2) void gemm8(
    const unsigned short* __restrict__ xb,
    const unsigned short* __restrict__ wb,
    const float* __restrict__ bias,
    float* __restrict__ C)
{
  __shared__ __align__(16) unsigned short As[2 * GBM * GBK];  // 64 KiB
  __shared__ __align__(16) unsigned short Bs[2 * GBN * GBK];  // 64 KiB
  char* ldsA = (char*)As;
  char* ldsB = (char*)Bs;

  // grid = 512 = 32 (tm) x 16 (tn); XCD swizzle, tn-fast within an XCD
  // (r7 layout: FETCH ~295 MB; tm-fast doubled it in r8).
  int bid = blockIdx.x;
  int swz = (bid & 7) * 64 + (bid >> 3);
  int tn = swz & 15, tm = swz >> 4;
  const int trow0 = tm * GBM;
  const int tcol0 = tn * GBN;

  int tid  = threadIdx.x;
  int lane = tid & 63;
  int wid  = tid >> 6;
  int wr = wid >> 2, wc = wid & 3;   // wave coords: 2 x 4
  int lr = lane & 15;                // fragment row/col
  int lg = lane >> 4;                // k-group (8 bf16 = 16B)
  const int sw = (lr & 7) << 4;      // swizzle byte term
  const int arow0 = (wr * 128 + lr) * 128;  // A row base bytes
  const int brow0 = (wc * 64  + lr) * 128;  // B row base bytes

  // staging geometry: granule l covers rows r0 + 64*l; const col group
  const int r0   = tid >> 3;
  const int colg = (tid & 7) ^ (r0 & 7);
  const unsigned short* sA = xb + (size_t)(trow0 + r0) * MM + colg * 8;
  const unsigned short* sB = wb + (size_t)(tcol0 + r0) * MM + colg * 8;
  const int dstb = tid * 16;

  f32x4 acc[8][4];
  #pragma unroll
  for (int i = 0; i < 8; i++)
    #pragma unroll
    for (int j = 0; j < 4; j++) {
      f32x4 z = {0.f, 0.f, 0.f, 0.f};
      acc[i][j] = z;
    }

  // ---- prologue: t0 full -> buf0; t1 A0,A1,B0 -> buf1 (7 half-tiles);
  //      vmcnt(6) retires t0's 4, leaves t1's 3 in flight ----
  STG_A(0, 0, 0); STG_A(0, 0, 1); STG_B(0, 0, 0); STG_B(0, 0, 1);
  STG_A(GBK, 1, 0); STG_A(GBK, 1, 1); STG_B(GBK, 1, 0);
  asm volatile("s_waitcnt vmcnt(6)" ::: "memory");
  __builtin_amdgcn_s_barrier();

  // ---- main loop: iters (t, t+1), t = 0..60 step 2; stages t+2, t+3 ----
  #pragma unroll 1
  for (int t = 0; t < NTK - 2; t += 2) {
    TILE4(t, 0,
          STG_B((t + 1) * GBK, 1, 1),   // P1: B1(t+1)
          STG_A((t + 2) * GBK, 0, 0),   // P2: A0(t+2)
          STG_A((t + 2) * GBK, 0, 1),   // P3: A1(t+2)
          STG_B((t + 2) * GBK, 0, 0),   // P4: B0(t+2)
          GATE6);
    TILE4(t + 1, 1,
          STG_B((t + 2) * GBK, 0, 1),   // P5: B1(t+2)
          STG_A((t + 3) * GBK, 1, 0),   // P6: A0(t+3)
          STG_A((t + 3) * GBK, 1, 1),   // P7: A1(t+3)
          STG_B((t + 3) * GBK, 1, 0),   // P8: B0(t+3)
          GATE6);
  }
  // ---- tail: tile 62 stages only B1(63), drains; tile 63 compute-only ----
  TILE4(NTK - 2, 0,
        STG_B((NTK - 1) * GBK, 1, 1),   // B1(63)
        NOST, NOST, NOST, GATE0v);
  TILE4(NTK - 1, 1, NOST, NOST, NOST, NOST, GNONE);

  // ---- epilogue: C/D layout col = lane&15, row = (lane>>4)*4 + reg ----
  #pragma unroll
  for (int ni = 0; ni < 4; ++ni) {
    int col = tcol0 + wc * 64 + ni * 16 + lr;
    float bi = bias[col];
    #pragma unroll
    for (int mi = 0; mi < 8; ++mi) {
      int rr0 = trow0 + wr * 128 + mi * 16 + lg * 4;
      #pragma unroll
      for (int qq = 0; qq < 4; ++qq)
        C[(size_t)(rr0 + qq) * NN + col] = acc[mi][ni][qq] + bi;
    }
  }
}

// ---------------------------------------------------------------------------
// Kernel 5b (fallback, ws too small for xb): m97-style 128x128 GEMM with
// inline f32->bf16 A-staging.
// ---------------------------------------------------------------------------
constexpr int BM = 128, BN = 128, BK = 64;

__global__ __launch_bounds__(256) void gemm_fb(
    const float* __restrict__ xf,
    const unsigned short* __restrict__ wb, const float* __restrict__ bias,
    float* __restrict__ C)
{
  __shared__ __align__(16) unsigned short As2[BM * BK];
  __shared__ __align__(16) unsigned short Bs2[BN * BK];

  int bid = blockIdx.x;
  int swz = (bid & 7) * 256 + (bid >> 3);
  int tn = swz & 31;
  int tm = swz >> 5;

  int tid  = threadIdx.x;
  int lane = tid & 63;
  int wid  = tid >> 6;
  int wr = wid >> 1, wc = wid & 1;
  int lr = lane & 15;
  int lg = lane >> 4;

  f32x4 acc[4][4];
  #pragma unroll
  for (int i = 0; i < 4; i++)
    #pragma unroll
    for (int j = 0; j < 4; j++) {
      f32x4 z = {0.f, 0.f, 0.f, 0.f};
      acc[i][j] = z;
    }

  int srow = tid >> 3;
  int scol = (tid & 7) * 8;
  const size_t a_base = (size_t)(tm * BM) * MM;
  const size_t b_base = (size_t)(tn * BN) * MM;

  for (int k0 = 0; k0 < MM; k0 += BK) {
    #pragma unroll
    for (int c = 0; c < 4; c++) {
      int row = c * 32 + srow;
      gl_lds16(wb + b_base + (size_t)row * MM + k0 + scol,
               (char*)Bs2 + (c * 256 + wid * 64) * 16);
    }
    #pragma unroll
    for (int c = 0; c < 4; c++) {
      int row = c * 32 + srow;
      const float* s = xf + a_base + (size_t)row * MM + k0 + scol;
      f32x4 v0 = *(const f32x4*)s;
      f32x4 v1 = *(const f32x4*)(s + 4);
      ushort8 p;
      p[0] = f2bf(v0.x); p[1] = f2bf(v0.y); p[2] = f2bf(v0.z); p[3] = f2bf(v0.w);
      p[4] = f2bf(v1.x); p[5] = f2bf(v1.y); p[6] = f2bf(v1.z); p[7] = f2bf(v1.w);
      *(ushort8*)&As2[(c * 256 + tid) * 8] = p;
    }
    __syncthreads();

    #pragma unroll
    for (int kk = 0; kk < 2; kk++) {
      bf16x8 a[4], b[4];
      #pragma unroll
      for (int i = 0; i < 4; i++) {
        a[i] = *(const bf16x8*)&As2[(wr * 64 + i * 16 + lr) * BK + kk * 32 + lg * 8];
        b[i] = *(const bf16x8*)&Bs2[(wc * 64 + i * 16 + lr) * BK + kk * 32 + lg * 8];
      }
      #pragma unroll
      for (int i = 0; i < 4; i++)
        #pragma unroll
        for (int j = 0; j < 4; j++)
          acc[i][j] = __builtin_amdgcn_mfma_f32_16x16x32_bf16(a[i], b[j], acc[i][j], 0, 0, 0);
    }
    __syncthreads();
  }

  int gn0 = tn * BN + wc * 64;
  int gt0 = tm * BM + wr * 64;
  #pragma unroll
  for (int j = 0; j < 4; j++) {
    int gn = gn0 + j * 16 + lr;
    float bi = bias[gn];
    #pragma unroll
    for (int i = 0; i < 4; i++) {
      int t0 = gt0 + i * 16 + lg * 4;
      #pragma unroll
      for (int q = 0; q < 4; q++)
        C[(size_t)(t0 + q) * NN + gn] = acc[i][j][q] + bi;
    }
  }
}

// ---------------------------------------------------------------------------
extern "C" void kernel_launch(void* const* d_in, const int* in_sizes, int n_in,
                              void* d_out, int out_size, void* d_ws, size_t ws_size,
                              hipStream_t stream)
{
  const float* x    = (const float*)d_in[0];
  const float* W    = (const float*)d_in[1];
  const float* bias = (const float*)d_in[2];
  const float* thL  = (const float*)d_in[3];
  const float* thR  = (const float*)d_in[4];
  const float* elm  = (const float*)d_in[5];
  const float* brn  = (const float*)d_in[6];
  const int*   prL  = (const int*)d_in[7];
  const int*   prR  = (const int*)d_in[8];
  float* out = (float*)d_out;

  char* ws = (char*)d_ws;
  unsigned short* Wb = (unsigned short*)ws;          // N*M bf16 = 33.5 MB
  size_t off = (size_t)NN * MM * 2;
  float* colC = (float*)(ws + off); off += MM * 4;
  float* colS = (float*)(ws + off); off += MM * 4;
  int*   colP = (int*)  (ws + off); off += MM * 4;
  unsigned short* xb = (unsigned short*)(ws + off);  // T*M bf16 = 67 MB
  bool use_xb = ws_size >= off + (size_t)T_N * MM * 2;

  init_cols <<<16, 256, 0, stream>>>(colC, colS, colP);
  build_cols<<< 8, 256, 0, stream>>>(thR, prR, colC, colS, colP);

  if (use_xb) {
    weff_conv<<<S_L + 2048, 256, 0, stream>>>(W, brn, elm, thL, prL,
                                              colC, colS, colP, Wb, x, xb);
    gemm8<<<512, 512, 0, stream>>>(xb, Wb, bias, out);
  } else {
    weff_conv<<<S_L, 256, 0, stream>>>(W, brn, elm, thL, prL,
                                       colC, colS, colP, Wb, x, xb);
    gemm_fb<<<2048, 256, 0, stream>>>(x, Wb, bias, out);
  }
}

// Round 14
// 298.971 us; speedup vs baseline: 1.4152x; 1.0112x over previous
//
#include <hip/hip_runtime.h>
#include <cstdint>
#include <cstddef>

// Problem constants
constexpr int T_N = 8192;   // rows of x / out
constexpr int MM  = 4096;   // K (cols of x, cols of W)
constexpr int NN  = 4096;   // rows of W / cols of out
constexpr int S_L = 2048;
constexpr int S_R = 2048;
constexpr float EPS_ = 1e-6f;

typedef float  f32x4   __attribute__((ext_vector_type(4)));
typedef __bf16 bf16x8  __attribute__((ext_vector_type(8)));
typedef unsigned short ushort8 __attribute__((ext_vector_type(8)));

__device__ __forceinline__ unsigned short f2bf(float f) {
  unsigned int u = __float_as_uint(f);
  u += 0x7FFFu + ((u >> 16) & 1u);   // round-to-nearest-even
  return (unsigned short)(u >> 16);
}

// ---------------------------------------------------------------------------
// Kernel 1: column rotation maps from (pairs_R, theta_R).
// NOTE: 2*S_R == MM — the pairs are a full permutation of all columns, so
// every index is written exactly once; no identity-init pass is needed.
// ---------------------------------------------------------------------------
__global__ void build_cols(const float* __restrict__ thR, const int* __restrict__ prR,
                           float* colC, float* colS, int* colP) {
  int s = blockIdx.x * blockDim.x + threadIdx.x;
  if (s < S_R) {
    int i = prR[2*s], j = prR[2*s+1];
    float c = cosf(thR[s]), sn = sinf(thR[s]);
    colC[i] = c; colS[i] = -sn; colP[i] = j;
    colC[j] = c; colS[j] =  sn; colP[j] = i;
  }
}

// ---------------------------------------------------------------------------
// Kernel 2 (fused): bid < S_L  -> W_eff pair build;  bid >= S_L -> x -> bf16
// ---------------------------------------------------------------------------
__global__ __launch_bounds__(256) void weff_conv(
    const float* __restrict__ W, const float* __restrict__ brn, const float* __restrict__ elm,
    const float* __restrict__ thL, const int* __restrict__ prL,
    const float* __restrict__ colC, const float* __restrict__ colS, const int* __restrict__ colP,
    unsigned short* __restrict__ Wb,
    const float* __restrict__ x, unsigned short* __restrict__ xb)
{
  __shared__ __align__(16) float rI[MM];
  __shared__ __align__(16) float rJ[MM];
  __shared__ float red[8];

  int bid = blockIdx.x;
  int tid = threadIdx.x;

  if (bid >= S_L) {
    const size_t total = (size_t)T_N * MM / 8;
    for (size_t i = (size_t)(bid - S_L) * 256 + tid; i < total; i += 2048ull * 256ull) {
      const float* s = x + i * 8;
      f32x4 v0 = *(const f32x4*)s;
      f32x4 v1 = *(const f32x4*)(s + 4);
      ushort8 p;
      p[0] = f2bf(v0.x); p[1] = f2bf(v0.y); p[2] = f2bf(v0.z); p[3] = f2bf(v0.w);
      p[4] = f2bf(v1.x); p[5] = f2bf(v1.y); p[6] = f2bf(v1.z); p[7] = f2bf(v1.w);
      *(ushort8*)(xb + i * 8) = p;
    }
    return;
  }

  int s = bid;
  int i = prL[2*s], j = prL[2*s+1];
  float cl = cosf(thL[s]), sl = sinf(thL[s]);
  const float* Wi = W + (size_t)i * MM;
  const float* Wj = W + (size_t)j * MM;

  for (int m = tid * 4; m < MM; m += 1024) {
    *(f32x4*)&rI[m] = *(const f32x4*)&Wi[m];
    *(f32x4*)&rJ[m] = *(const f32x4*)&Wj[m];
  }
  __syncthreads();

  float ssi = 0.f, ssj = 0.f;
  for (int m = tid; m < MM; m += 256) {
    int p = colP[m];
    float c = colC[m], sn = colS[m];
    float vi = c * rI[m] + sn * rI[p];
    float vj = c * rJ[m] + sn * rJ[p];
    float ei = cl * vi - sl * vj;
    float ej = sl * vi + cl * vj;
    ssi += ei * ei;
    ssj += ej * ej;
  }
  #pragma unroll
  for (int o = 32; o; o >>= 1) { ssi += __shfl_xor(ssi, o); ssj += __shfl_xor(ssj, o); }
  int lane = tid & 63, wid = tid >> 6;
  if (lane == 0) { red[wid] = ssi; red[4 + wid] = ssj; }
  __syncthreads();
  float ti = red[0] + red[1] + red[2] + red[3];
  float tj = red[4] + red[5] + red[6] + red[7];
  float sci = brn[i] * expf(elm[i]) / sqrtf(ti + EPS_);
  float scj = brn[j] * expf(elm[j]) / sqrtf(tj + EPS_);

  for (int m0 = tid * 8; m0 < MM; m0 += 2048) {
    ushort8 pi, pj;
    #pragma unroll
    for (int q = 0; q < 8; q++) {
      int m = m0 + q;
      int p = colP[m];
      float c = colC[m], sn = colS[m];
      float vi = c * rI[m] + sn * rI[p];
      float vj = c * rJ[m] + sn * rJ[p];
      pi[q] = f2bf((cl * vi - sl * vj) * sci);
      pj[q] = f2bf((sl * vi + cl * vj) * scj);
    }
    *(ushort8*)&Wb[(size_t)i * MM + m0] = pi;
    *(ushort8*)&Wb[(size_t)j * MM + m0] = pj;
  }
}

// ---------------------------------------------------------------------------
// global->LDS async staging helper (16B, linear LDS dest)
// ---------------------------------------------------------------------------
typedef const __attribute__((address_space(1))) unsigned int* as1_u32p;
typedef __attribute__((address_space(3))) unsigned int* as3_u32p;

__device__ __forceinline__ void gl_lds16(const void* g, void* l) {
  __builtin_amdgcn_global_load_lds((as1_u32p)g, (as3_u32p)l, 16, 0, 0);
}

// ---------------------------------------------------------------------------
// Kernel 3: 256x256 GEMM — exact m201 8-phase slot schedule (best measured:
//   242 us, MfmaUtil 50.3%, 0 bank conflicts — rounds 9/13).
//   BK=64, 8 waves (2Mx4N), per-wave 128x64, acc[8][4], 16x16x32 bf16 MFMA.
//   LDS 128 KiB dbuf.  8 phases per 2 K-tiles; each phase:
//     {ds_reads(12/8/4/0), stage ONE half-tile (2 gl_lds)} -> [lgkm(8) if 12]
//     -> bar -> lgkm(0) -> setprio(1) 16 MFMA setprio(0) -> bar
//   Stage slots (tile t even, buffers: t&1):
//     P1: B1(t+1)  P2: A0(t+2)  P3: A1(t+2)  P4: B0(t+2)  [vmcnt(6)]
//     P5: B1(t+2)  P6: A0(t+3)  P7: A1(t+3)  P8: B0(t+3)  [vmcnt(6)]
//   Ledger: each gate leaves exactly 3 half-tiles in flight; a tile is fully
//   retired at the gate before the phase that reads it (RAW).  Every stage
//   targets the region whose last ds_read completed one phase-barrier
//   earlier (WAR).  Quadrants: P1 Q1=A0xB0, P2 Q2=A1xB0, P3 Q3=A1xB1,
//   P4 Q4=A0xB1 (held regs, zero reads -> LDS catch-up window).
//   Swizzle (r2-verified, 0 conflicts): stage src col-group ^= (row&7);
//   read byte addr: row*128 + ((kk*64+lg*16) ^ ((lr&7)<<4)).
// ---------------------------------------------------------------------------
constexpr int GBM = 256, GBN = 256, GBK = 64;
constexpr int NTK = MM / GBK;              // 64 K-tiles
constexpr int BUFB = GBM * GBK * 2;        // 32 KiB per operand per buffer

#define SB0() __builtin_amdgcn_sched_barrier(0)
#define BAR() __builtin_amdgcn_s_barrier()
#define LGKM(N) do { asm volatile("s_waitcnt lgkmcnt(" #N ")" ::: "memory"); \
                     SB0(); } while (0)

#define RD_A8(DST, AB, MIH)                                                   \
  _Pragma("unroll") for (int i_ = 0; i_ < 4; ++i_)                            \
  _Pragma("unroll") for (int k_ = 0; k_ < 2; ++k_)                            \
    DST[i_][k_] = *(const bf16x8*)((AB) + arow0 + ((MIH) * 4 + i_) * 2048     \
                                    + ((k_ * 64 + lg * 16) ^ sw));

#define RD_B4(DST, BB, NIH)                                                   \
  _Pragma("unroll") for (int n_ = 0; n_ < 2; ++n_)                            \
  _Pragma("unroll") for (int k_ = 0; k_ < 2; ++k_)                            \
    DST[n_][k_] = *(const bf16x8*)((BB) + brow0 + ((NIH) * 2 + n_) * 2048     \
                                    + ((k_ * 64 + lg * 16) ^ sw));

#define QMF(AF, BF, MI0, NI0)                                                 \
  __builtin_amdgcn_s_setprio(1);                                              \
  _Pragma("unroll") for (int k_ = 0; k_ < 2; ++k_)                            \
  _Pragma("unroll") for (int i_ = 0; i_ < 4; ++i_)                            \
  _Pragma("unroll") for (int n_ = 0; n_ < 2; ++n_)                            \
    acc[(MI0) + i_][(NI0) + n_] = __builtin_amdgcn_mfma_f32_16x16x32_bf16(    \
        AF[i_][k_], BF[n_][k_], acc[(MI0) + i_][(NI0) + n_], 0, 0, 0);        \
  __builtin_amdgcn_s_setprio(0);

#define STG_A(KOF, BUF, H)                                                    \
  _Pragma("unroll") for (int l_ = 2 * (H); l_ < 2 * (H) + 2; ++l_)            \
    gl_lds16(sA + (size_t)l_ * (64 * MM) + (KOF),                             \
             ldsA + (BUF) * BUFB + dstb + l_ * 8192);
#define STG_B(KOF, BUF, H)                                                    \
  _Pragma("unroll") for (int l_ = 2 * (H); l_ < 2 * (H) + 2; ++l_)            \
    gl_lds16(sB + (size_t)l_ * (64 * MM) + (KOF),                             \
             ldsB + (BUF) * BUFB + dstb + l_ * 8192);

#define GATE6  asm volatile("s_waitcnt vmcnt(6)" ::: "memory")
#define GATE0v asm volatile("s_waitcnt vmcnt(0)" ::: "memory")
#define GNONE  do { } while (0)
#define NOST   do { } while (0)

// One K-tile = 4 phases.  ST1..ST4 are half-tile stage statements (or NOST);
// GATE fires in P4 before its barrier.
#define TILE4(T, BB, ST1, ST2, ST3, ST4, GATE)                                \
  {                                                                           \
    const char* Ab_ = ldsA + (BB) * BUFB;                                     \
    const char* Bb_ = ldsB + (BB) * BUFB;                                     \
    bf16x8 a0[4][2], a1[4][2], b0[2][2], b1[2][2];                            \
    /* P1: 12 reads; stage ST1; lgkm(8); Q1 = A0 x B0 */                      \
    RD_B4(b0, Bb_, 0);                                                        \
    RD_A8(a0, Ab_, 0);                                                        \
    SB0();                                                                    \
    ST1;                                                                      \
    LGKM(8);                                                                  \
    BAR();                                                                    \
    LGKM(0);                                                                  \
    QMF(a0, b0, 0, 0);                                                        \
    BAR();                                                                    \
    /* P2: 8 reads; stage ST2; Q2 = A1 x B0 */                                \
    RD_A8(a1, Ab_, 1);                                                        \
    SB0();                                                                    \
    ST2;                                                                      \
    BAR();                                                                    \
    LGKM(0);                                                                  \
    QMF(a1, b0, 4, 0);                                                        \
    BAR();                                                                    \
    /* P3: 4 reads; stage ST3; Q3 = A1 x B1 */                                \
    RD_B4(b1, Bb_, 1);                                                        \
    SB0();                                                                    \
    ST3;                                                                      \
    BAR();                                                                    \
    LGKM(0);                                                                  \
    QMF(a1, b1, 4, 2);                                                        \
    BAR();                                                                    \
    /* P4: 0 reads; stage ST4; gate; Q4 = A0 x B1 (held regs) */              \
    ST4;                                                                      \
    GATE;                                                                     \
    BAR();                                                                    \
    QMF(a0, b1, 0, 2);                                                        \
    BAR();                                                                    \
  }

__global__ __launch_bounds__(512, 2) void gemm8(
    const unsigned short* __restrict__ xb,
    const unsigned short* __restrict__ wb,
    const float* __restrict__ bias,
    float* __restrict__ C)
{
  __shared__ __align__(16) unsigned short As[2 * GBM * GBK];  // 64 KiB
  __shared__ __align__(16) unsigned short Bs[2 * GBN * GBK];  // 64 KiB
  char* ldsA = (char*)As;
  char* ldsB = (char*)Bs;

  // grid = 512 = 32 (tm) x 16 (tn); XCD swizzle, tn-fast within an XCD
  // (r7 layout: FETCH ~295 MB; tm-fast doubled it in r8).
  int bid = blockIdx.x;
  int swz = (bid & 7) * 64 + (bid >> 3);
  int tn = swz & 15, tm = swz >> 4;
  const int trow0 = tm * GBM;
  const int tcol0 = tn * GBN;

  int tid  = threadIdx.x;
  int lane = tid & 63;
  int wid  = tid >> 6;
  int wr = wid >> 2, wc = wid & 3;   // wave coords: 2 x 4
  int lr = lane & 15;                // fragment row/col
  int lg = lane >> 4;                // k-group (8 bf16 = 16B)
  const int sw = (lr & 7) << 4;      // swizzle byte term
  const int arow0 = (wr * 128 + lr) * 128;  // A row base bytes
  const int brow0 = (wc * 64  + lr) * 128;  // B row base bytes

  // staging geometry: granule l covers rows r0 + 64*l; const col group
  const int r0   = tid >> 3;
  const int colg = (tid & 7) ^ (r0 & 7);
  const unsigned short* sA = xb + (size_t)(trow0 + r0) * MM + colg * 8;
  const unsigned short* sB = wb + (size_t)(tcol0 + r0) * MM + colg * 8;
  const int dstb = tid * 16;

  f32x4 acc[8][4];
  #pragma unroll
  for (int i = 0; i < 8; i++)
    #pragma unroll
    for (int j = 0; j < 4; j++) {
      f32x4 z = {0.f, 0.f, 0.f, 0.f};
      acc[i][j] = z;
    }

  // ---- prologue: t0 full -> buf0; t1 A0,A1,B0 -> buf1 (7 half-tiles);
  //      vmcnt(6) retires t0's 4, leaves t1's 3 in flight ----
  STG_A(0, 0, 0); STG_A(0, 0, 1); STG_B(0, 0, 0); STG_B(0, 0, 1);
  STG_A(GBK, 1, 0); STG_A(GBK, 1, 1); STG_B(GBK, 1, 0);
  asm volatile("s_waitcnt vmcnt(6)" ::: "memory");
  __builtin_amdgcn_s_barrier();

  // ---- main loop: iters (t, t+1), t = 0..60 step 2; stages t+2, t+3 ----
  #pragma unroll 1
  for (int t = 0; t < NTK - 2; t += 2) {
    TILE4(t, 0,
          STG_B((t + 1) * GBK, 1, 1),   // P1: B1(t+1)
          STG_A((t + 2) * GBK, 0, 0),   // P2: A0(t+2)
          STG_A((t + 2) * GBK, 0, 1),   // P3: A1(t+2)
          STG_B((t + 2) * GBK, 0, 0),   // P4: B0(t+2)
          GATE6);
    TILE4(t + 1, 1,
          STG_B((t + 2) * GBK, 0, 1),   // P5: B1(t+2)
          STG_A((t + 3) * GBK, 1, 0),   // P6: A0(t+3)
          STG_A((t + 3) * GBK, 1, 1),   // P7: A1(t+3)
          STG_B((t + 3) * GBK, 1, 0),   // P8: B0(t+3)
          GATE6);
  }
  // ---- tail: tile 62 stages only B1(63), drains; tile 63 compute-only ----
  TILE4(NTK - 2, 0,
        STG_B((NTK - 1) * GBK, 1, 1),   // B1(63)
        NOST, NOST, NOST, GATE0v);
  TILE4(NTK - 1, 1, NOST, NOST, NOST, NOST, GNONE);

  // ---- epilogue: C/D layout col = lane&15, row = (lane>>4)*4 + reg ----
  #pragma unroll
  for (int ni = 0; ni < 4; ++ni) {
    int col = tcol0 + wc * 64 + ni * 16 + lr;
    float bi = bias[col];
    #pragma unroll
    for (int mi = 0; mi < 8; ++mi) {
      int rr0 = trow0 + wr * 128 + mi * 16 + lg * 4;
      #pragma unroll
      for (int qq = 0; qq < 4; ++qq)
        C[(size_t)(rr0 + qq) * NN + col] = acc[mi][ni][qq] + bi;
    }
  }
}

// ---------------------------------------------------------------------------
// Kernel 3b (fallback, ws too small for xb): m97-style 128x128 GEMM with
// inline f32->bf16 A-staging.
// ---------------------------------------------------------------------------
constexpr int BM = 128, BN = 128, BK = 64;

__global__ __launch_bounds__(256) void gemm_fb(
    const float* __restrict__ xf,
    const unsigned short* __restrict__ wb, const float* __restrict__ bias,
    float* __restrict__ C)
{
  __shared__ __align__(16) unsigned short As2[BM * BK];
  __shared__ __align__(16) unsigned short Bs2[BN * BK];

  int bid = blockIdx.x;
  int swz = (bid & 7) * 256 + (bid >> 3);
  int tn = swz & 31;
  int tm = swz >> 5;

  int tid  = threadIdx.x;
  int lane = tid & 63;
  int wid  = tid >> 6;
  int wr = wid >> 1, wc = wid & 1;
  int lr = lane & 15;
  int lg = lane >> 4;

  f32x4 acc[4][4];
  #pragma unroll
  for (int i = 0; i < 4; i++)
    #pragma unroll
    for (int j = 0; j < 4; j++) {
      f32x4 z = {0.f, 0.f, 0.f, 0.f};
      acc[i][j] = z;
    }

  int srow = tid >> 3;
  int scol = (tid & 7) * 8;
  const size_t a_base = (size_t)(tm * BM) * MM;
  const size_t b_base = (size_t)(tn * BN) * MM;

  for (int k0 = 0; k0 < MM; k0 += BK) {
    #pragma unroll
    for (int c = 0; c < 4; c++) {
      int row = c * 32 + srow;
      gl_lds16(wb + b_base + (size_t)row * MM + k0 + scol,
               (char*)Bs2 + (c * 256 + wid * 64) * 16);
    }
    #pragma unroll
    for (int c = 0; c < 4; c++) {
      int row = c * 32 + srow;
      const float* s = xf + a_base + (size_t)row * MM + k0 + scol;
      f32x4 v0 = *(const f32x4*)s;
      f32x4 v1 = *(const f32x4*)(s + 4);
      ushort8 p;
      p[0] = f2bf(v0.x); p[1] = f2bf(v0.y); p[2] = f2bf(v0.z); p[3] = f2bf(v0.w);
      p[4] = f2bf(v1.x); p[5] = f2bf(v1.y); p[6] = f2bf(v1.z); p[7] = f2bf(v1.w);
      *(ushort8*)&As2[(c * 256 + tid) * 8] = p;
    }
    __syncthreads();

    #pragma unroll
    for (int kk = 0; kk < 2; kk++) {
      bf16x8 a[4], b[4];
      #pragma unroll
      for (int i = 0; i < 4; i++) {
        a[i] = *(const bf16x8*)&As2[(wr * 64 + i * 16 + lr) * BK + kk * 32 + lg * 8];
        b[i] = *(const bf16x8*)&Bs2[(wc * 64 + i * 16 + lr) * BK + kk * 32 + lg * 8];
      }
      #pragma unroll
      for (int i = 0; i < 4; i++)
        #pragma unroll
        for (int j = 0; j < 4; j++)
          acc[i][j] = __builtin_amdgcn_mfma_f32_16x16x32_bf16(a[i], b[j], acc[i][j], 0, 0, 0);
    }
    __syncthreads();
  }

  int gn0 = tn * BN + wc * 64;
  int gt0 = tm * BM + wr * 64;
  #pragma unroll
  for (int j = 0; j < 4; j++) {
    int gn = gn0 + j * 16 + lr;
    float bi = bias[gn];
    #pragma unroll
    for (int i = 0; i < 4; i++) {
      int t0 = gt0 + i * 16 + lg * 4;
      #pragma unroll
      for (int q = 0; q < 4; q++)
        C[(size_t)(t0 + q) * NN + gn] = acc[i][j][q] + bi;
    }
  }
}

// ---------------------------------------------------------------------------
extern "C" void kernel_launch(void* const* d_in, const int* in_sizes, int n_in,
                              void* d_out, int out_size, void* d_ws, size_t ws_size,
                              hipStream_t stream)
{
  const float* x    = (const float*)d_in[0];
  const float* W    = (const float*)d_in[1];
  const float* bias = (const float*)d_in[2];
  const float* thL  = (const float*)d_in[3];
  const float* thR  = (const float*)d_in[4];
  const float* elm  = (const float*)d_in[5];
  const float* brn  = (const float*)d_in[6];
  const int*   prL  = (const int*)d_in[7];
  const int*   prR  = (const int*)d_in[8];
  float* out = (float*)d_out;

  char* ws = (char*)d_ws;
  unsigned short* Wb = (unsigned short*)ws;          // N*M bf16 = 33.5 MB
  size_t off = (size_t)NN * MM * 2;
  float* colC = (float*)(ws + off); off += MM * 4;
  float* colS = (float*)(ws + off); off += MM * 4;
  int*   colP = (int*)  (ws + off); off += MM * 4;
  unsigned short* xb = (unsigned short*)(ws + off);  // T*M bf16 = 67 MB
  bool use_xb = ws_size >= off + (size_t)T_N * MM * 2;

  build_cols<<<8, 256, 0, stream>>>(thR, prR, colC, colS, colP);

  if (use_xb) {
    weff_conv<<<S_L + 2048, 256, 0, stream>>>(W, brn, elm, thL, prL,
                                              colC, colS, colP, Wb, x, xb);
    gemm8<<<512, 512, 0, stream>>>(xb, Wb, bias, out);
  } else {
    weff_conv<<<S_L, 256, 0, stream>>>(W, brn, elm, thL, prL,
                                       colC, colS, colP, Wb, x, xb);
    gemm_fb<<<2048, 256, 0, stream>>>(x, Wb, bias, out);
  }
}